// Round 2
// baseline (475.319 us; speedup 1.0000x reference)
//
#include <hip/hip_runtime.h>
#include <hip/hip_bf16.h>
#include <hip/hip_fp16.h>

// Codebook argmin: x (32768,512) fp32, codebook (8192,512) fp32 -> codes (32768) int32
//
// v9: 256x256-tile coarse pass (m201-style). Staged bytes are the wall:
// v8 staged 2*M*N*K/128 = 2.15 GB at the ~8.5 TB/s GL2LDS/L3 effective rate.
// Doubling the tile edge halves staging to 1.07 GB. 512 thr = 8 waves (2x4),
// wave-tile 128x64 (acc 8x4 f32x4 = 128 VGPR), LDS 128 KB = 2 x (32K A+32K B),
// BK=128 chunks, depth-2 prefetch with counted vmcnt(8) + raw s_barrier
// (never drain to 0 in-loop). Epilogue: 4 wn-passes over a 256-row table.
// part shrinks to 32 slices.
//
// ws layout:
//   ch8  : fp8 [8192][512]   @ 0        (4 MB)
//   xh8  : fp8 [32768][512]  @ 4 MB     (16 MB)
//   cnh  : f32 [8192]        @ 20 MB    (32 KB)
//   cand : int [32768][8]    @ 20M+32K  (1 MB)
//   part : uint4 [32][32768] @ 22 MB    (16 MB)

#define M_ROWS 32768
#define DDIM   512
#define KCODES 8192
#define NCAND  8

typedef unsigned long long u64;
typedef unsigned int u32;
typedef __attribute__((ext_vector_type(4))) float f32x4;
typedef __attribute__((ext_vector_type(8))) int v8i;

#define GL2LDS(gp, lp) __builtin_amdgcn_global_load_lds(                  \
    (const __attribute__((address_space(1))) void*)(gp),                  \
    (__attribute__((address_space(3))) void*)(lp), 16, 0, 0)

__device__ __forceinline__ u32 umin32(u32 a, u32 b) { return a < b ? a : b; }
__device__ __forceinline__ u32 umax32(u32 a, u32 b) { return a > b ? a : b; }
__device__ __forceinline__ u64 umin64(u64 a, u64 b) { return a < b ? a : b; }
__device__ __forceinline__ u32 umin3(u32 a, u32 b, u32 c) {  // fuses to v_min3_u32
  return umin32(umin32(a, b), c);
}
__device__ __forceinline__ u32 med3u(u32 a, u32 b, u32 c) {
  u32 d;
  asm("v_med3_u32 %0, %1, %2, %3" : "=v"(d) : "v"(a), "v"(b), "v"(c));
  return d;
}

// float -> order-preserving u32 (ascending); used only in rescore
__device__ __forceinline__ u32 fsort(float s) {
  u32 fb = __float_as_uint(s);
  return fb ^ (u32)(((int)fb >> 31) | 0x80000000);
}

// 8 floats -> 8 packed e4m3 bytes (uint2)
__device__ __forceinline__ uint2 pk8_fp8(float4 v0, float4 v1) {
  int lo = 0, hi = 0;
  lo = __builtin_amdgcn_cvt_pk_fp8_f32(v0.x, v0.y, lo, false);
  lo = __builtin_amdgcn_cvt_pk_fp8_f32(v0.z, v0.w, lo, true);
  hi = __builtin_amdgcn_cvt_pk_fp8_f32(v1.x, v1.y, hi, false);
  hi = __builtin_amdgcn_cvt_pk_fp8_f32(v1.z, v1.w, hi, true);
  return (uint2){(u32)lo, (u32)hi};
}

// ---------------------------------------------------------------- conv codebook
__global__ __launch_bounds__(256) void conv_codebook_kernel(
    const float* __restrict__ cb, unsigned char* __restrict__ ch8,
    float* __restrict__ cnh) {
  int wave = (blockIdx.x * 256 + threadIdx.x) >> 6;
  int lane = threadIdx.x & 63;
  if (wave >= KCODES) return;
  const float* src = cb + (size_t)wave * DDIM + lane * 8;
  float4 v0 = *(const float4*)(src);
  float4 v1 = *(const float4*)(src + 4);
  *(uint2*)(ch8 + (size_t)wave * DDIM + lane * 8) = pk8_fp8(v0, v1);
  float ss = v0.x*v0.x + v0.y*v0.y + v0.z*v0.z + v0.w*v0.w
           + v1.x*v1.x + v1.y*v1.y + v1.z*v1.z + v1.w*v1.w;
#pragma unroll
  for (int off = 32; off; off >>= 1) ss += __shfl_xor(ss, off);
  if (lane == 0) cnh[wave] = 0.5f * ss;
}

// ---------------------------------------------------------------- conv x
__global__ __launch_bounds__(256) void conv_x_kernel(
    const float* __restrict__ x, unsigned char* __restrict__ xh8) {
  size_t i = ((size_t)blockIdx.x * 256 + threadIdx.x) * 8;
  float4 v0 = *(const float4*)(x + i);
  float4 v1 = *(const float4*)(x + i + 4);
  *(uint2*)(xh8 + i) = pk8_fp8(v0, v1);
}

// LDS fragment load for K=128 MFMA: lane needs global k-bytes g*32..g*32+31
// of row `row` = granules q=g*2, g*2+1. LDS[row][slot]=global[row][slot^(row&7)]
// -> read slots (g*2)^(row&7) and that ^1. Combine two b128s into v8i.
__device__ __forceinline__ v8i ld_frag(const char* L, int row, int g) {
  const int base = row * 128;
  const int sl = ((g * 2) ^ (row & 7)) * 16;
  int4 lo = *(const int4*)&L[base + sl];
  int4 hi = *(const int4*)&L[base + (sl ^ 16)];
  v8i r;
  r[0] = lo.x; r[1] = lo.y; r[2] = lo.z; r[3] = lo.w;
  r[4] = hi.x; r[5] = hi.y; r[6] = hi.z; r[7] = hi.w;
  return r;
}

// ---------------------------------------------------------------- coarse GEMM
// Block: 512 threads = 8 waves as 2x4 (wm,wn); wave = 128x64 outputs as 8x4
// grid of 16x16x128 scaled-fp8 MFMA (scales = 1.0 -> exact e4m3 math).
// K=512 in 4 chunks of BK=128 bytes, double-buffered, depth-2 prefetch,
// counted vmcnt(8) (= one chunk's 8 GL2LDS per wave stays in flight).
__global__ __launch_bounds__(512, 2) void coarse_kernel(
    const unsigned char* __restrict__ xh8, const unsigned char* __restrict__ ch8,
    const float* __restrict__ cnh, uint4* __restrict__ part) {
  // 131072 B: 2 x {aL(32K)+bL(32K)}; epilogue tab[256][17] uint4 (69632 B)
  // overlays (written only after all K-loop reads complete).
  __shared__ __align__(16) char smem[131072];
  uint4* tab = (uint4*)smem;

  const int tid  = threadIdx.x;
  const int lane = tid & 63;
  const int wid  = tid >> 6;
  const int wm   = wid >> 2, wn = wid & 3;
  const int g    = lane >> 4, l16 = lane & 15;

  const int mblk = blockIdx.x & 127;
  const int nblk = blockIdx.x >> 7;
  const int row0 = mblk * 256;
  const int col0 = nblk * 256;

  const int a_ = lane >> 3, b_ = lane & 7;
  // per-lane GL2LDS source: row +a_, granule b_^a_ of the current chunk
  const size_t gsrc = (size_t)a_ * DDIM + ((b_ ^ a_) << 4);
  const unsigned char* abase = xh8 + (size_t)row0 * DDIM + gsrc;
  const unsigned char* bbase = ch8 + (size_t)col0 * DDIM + gsrc;

// stage chunk cc (256 rows x 128 k-bytes of A and B) into buffer `buf`:
// 8 GL2LDS per wave (4 A + 4 B), wave wid covers rows [wid*32, wid*32+32)
#define STAGE(cc, buf) do {                                               \
    char* base_ = smem + (buf) * 65536;                                   \
    _Pragma("unroll")                                                     \
    for (int j = 0; j < 4; ++j) {                                         \
      const int R_ = wid * 32 + j * 8;                                    \
      const size_t off_ = (size_t)R_ * DDIM + (size_t)(cc) * 128;         \
      GL2LDS(abase + off_, base_ + R_ * 128);                             \
      GL2LDS(bbase + off_, base_ + 32768 + R_ * 128);                     \
    }                                                                     \
  } while (0)

#define WAITV(n) asm volatile("s_waitcnt vmcnt(" #n ")" ::: "memory")
#define RBAR() do {                                                       \
    __builtin_amdgcn_sched_barrier(0);                                    \
    __builtin_amdgcn_s_barrier();                                         \
    __builtin_amdgcn_sched_barrier(0);                                    \
  } while (0)

#define COMPUTE(c) do {                                                   \
    const char* aL_ = smem + ((c) & 1) * 65536;                           \
    const char* bL_ = aL_ + 32768;                                        \
    v8i af[8];                                                            \
    _Pragma("unroll")                                                     \
    for (int t = 0; t < 8; ++t)                                           \
      af[t] = ld_frag(aL_, wm * 128 + t * 16 + l16, g);                   \
    _Pragma("unroll")                                                     \
    for (int tn = 0; tn < 4; ++tn) {                                      \
      v8i bf = ld_frag(bL_, wn * 64 + tn * 16 + l16, g);                  \
      _Pragma("unroll")                                                   \
      for (int tm = 0; tm < 8; ++tm)                                      \
        acc[tm][tn] = __builtin_amdgcn_mfma_scale_f32_16x16x128_f8f6f4(   \
            af[tm], bf, acc[tm][tn],                                      \
            0, 0,                     /* cbsz, blgp = fp8(e4m3) */        \
            0, 0x7F7F7F7F,            /* opsel_a, scale_a = 1.0 */        \
            0, 0x7F7F7F7F);           /* opsel_b, scale_b = 1.0 */        \
    }                                                                     \
  } while (0)

  // codes + half-norms for this wave's 64 columns (vmem issued before the
  // stages -> drained by the first vmcnt(8), never miscounts the chunks).
  u32 codev[4];
  float cn[4];
#pragma unroll
  for (int tn = 0; tn < 4; ++tn) {
    codev[tn] = (u32)(col0 + wn * 64 + tn * 16 + l16);
    cn[tn] = cnh[codev[tn]];
  }

  f32x4 acc[8][4];
#pragma unroll
  for (int tm = 0; tm < 8; ++tm)
#pragma unroll
    for (int tn = 0; tn < 4; ++tn) acc[tm][tn] = (f32x4){0.f, 0.f, 0.f, 0.f};

  STAGE(0, 0);
  STAGE(1, 1);

  WAITV(8);  RBAR();        // chunk0 landed (chunk1 stays in flight)
  COMPUTE(0);
  RBAR();                   // all waves done reading buf0
  STAGE(2, 0);

  WAITV(8);  RBAR();        // chunk1 landed (chunk2 in flight)
  COMPUTE(1);
  RBAR();                   // all waves done reading buf1
  STAGE(3, 1);

  WAITV(8);  RBAR();        // chunk2 landed (chunk3 in flight)
  COMPUTE(2);
  // no overwrite of buf0 follows -> no barrier needed here

  WAITV(0);  RBAR();        // chunk3 landed
  COMPUTE(3);

  // ---- epilogue phase 1: per-lane top-3 u32 keys over 4 cols x 32 rows ----
  // key = float_bits(s) & ~0x1FFF | code. s > 0 by 8-sigma margin.
  // Pair-insertion via min3/med3: top-3 of {a1<=a2<=a3, lo<=hi} is
  //   a1' = min(a1,lo); m = max(a1,lo);
  //   a2' = min3(a2,m,hi); a3' = min(a3, med3(a2,m,hi)).
  u32 k1[32], k2[32], k3[32];
#pragma unroll
  for (int tm = 0; tm < 8; ++tm)
#pragma unroll
    for (int r = 0; r < 4; ++r) {
      const int sl = tm * 4 + r;
      u32 key[4];
#pragma unroll
      for (int tn = 0; tn < 4; ++tn) {
        float s = cn[tn] - acc[tm][tn][r];
        key[tn] = (__float_as_uint(s) & 0xFFFFE000u) | codev[tn];
      }
      u32 a1 = umin32(key[0], key[1]);
      u32 a2 = umax32(key[0], key[1]);
      u32 a3 = ~0u;
      {
        u32 lo = umin32(key[2], key[3]), hi = umax32(key[2], key[3]);
        u32 m  = umax32(a1, lo);
        a1 = umin32(a1, lo);
        u32 b3 = med3u(a2, m, hi);
        a2 = umin3(a2, m, hi);
        a3 = umin32(a3, b3);
      }
      k1[sl] = a1; k2[sl] = a2; k3[sl] = a3;
    }

  // ---- epilogue phase 2: LDS-table reduce, four wn passes ----
  // merge sorted {v.x<=v.y<=v.z} into running sorted {m1<=m2<=m3}:
  //   m1' = min(m1,x); a = max(m1,x);
  //   m2' = min3(m2,a,y); m3' = min3(m3, med3(m2,a,y), z).
  u32 m1 = ~0u, m2 = ~0u, m3 = ~0u;
#pragma unroll
  for (int p = 0; p < 4; ++p) {
    __syncthreads();
    if (wn == p) {
#pragma unroll
      for (int tm = 0; tm < 8; ++tm)
#pragma unroll
        for (int r = 0; r < 4; ++r) {
          const int row = wm * 128 + tm * 16 + g * 4 + r;
          const int sl = tm * 4 + r;
          tab[row * 17 + l16] = (uint4){k1[sl], k2[sl], k3[sl], 0u};
        }
    }
    __syncthreads();
    if (tid < 256) {
#pragma unroll
      for (int e = 0; e < 16; ++e) {
        uint4 v = tab[tid * 17 + e];
        u32 a = umax32(m1, v.x);
        m1 = umin32(m1, v.x);
        u32 b = med3u(m2, a, v.y);
        m2 = umin3(m2, a, v.y);
        m3 = umin3(m3, b, v.z);
      }
    }
  }

  if (tid < 256)
    part[(size_t)nblk * M_ROWS + row0 + tid] = (uint4){m1, m2, m3, 0u};
#undef COMPUTE
#undef STAGE
#undef WAITV
#undef RBAR
}

// ---------------------------------------------------------------- merge: global top-8
__global__ __launch_bounds__(256) void merge_kernel(
    const uint4* __restrict__ part, int* __restrict__ cand) {
  const int row = blockIdx.x * 256 + threadIdx.x;
  u32 k[NCAND];
#pragma unroll
  for (int i = 0; i < NCAND; ++i) k[i] = ~0u;
  for (int nb = 0; nb < KCODES / 256; ++nb) {
    uint4 e = part[(size_t)nb * M_ROWS + row];
    u32 t = e.x;
#pragma unroll
    for (int i = 0; i < NCAND; ++i) { u32 mx = umax32(k[i], t); k[i] = umin32(k[i], t); t = mx; }
    t = e.y;
#pragma unroll
    for (int i = 0; i < NCAND; ++i) { u32 mx = umax32(k[i], t); k[i] = umin32(k[i], t); t = mx; }
    t = e.z;
#pragma unroll
    for (int i = 0; i < NCAND; ++i) { u32 mx = umax32(k[i], t); k[i] = umin32(k[i], t); t = mx; }
  }
#pragma unroll
  for (int i = 0; i < NCAND; ++i)
    cand[row * NCAND + i] = (int)(k[i] & 0x1FFFu);
}

// ---------------------------------------------------------------- fp32 rescore (8)
__global__ __launch_bounds__(256) void rescore_kernel(
    const float* __restrict__ x, const float* __restrict__ cb,
    const float* __restrict__ cnh, const int* __restrict__ cand,
    int* __restrict__ out) {
  int wave = (blockIdx.x * 256 + threadIdx.x) >> 6;
  int lane = threadIdx.x & 63;
  if (wave >= M_ROWS) return;
  int idx[NCAND];
#pragma unroll
  for (int j = 0; j < NCAND; ++j) idx[j] = cand[wave * NCAND + j];

  const float* xr = x + (size_t)wave * DDIM + lane * 8;
  float4 x0 = *(const float4*)(xr);
  float4 x1 = *(const float4*)(xr + 4);

  float d[NCAND];
#pragma unroll
  for (int j = 0; j < NCAND; ++j) {
    const float* c = cb + (size_t)idx[j] * DDIM + lane * 8;
    float4 a0 = *(const float4*)(c);
    float4 a1 = *(const float4*)(c + 4);
    d[j] = x0.x*a0.x + x0.y*a0.y + x0.z*a0.z + x0.w*a0.w
         + x1.x*a1.x + x1.y*a1.y + x1.z*a1.z + x1.w*a1.w;
  }
#pragma unroll
  for (int off = 32; off; off >>= 1)
#pragma unroll
    for (int j = 0; j < NCAND; ++j) d[j] += __shfl_xor(d[j], off);

  if (lane == 0) {
    u64 best = ~0ull;
#pragma unroll
    for (int j = 0; j < NCAND; ++j) {
      float s = cnh[idx[j]] - d[j];
      u64 key = ((u64)fsort(s) << 32) | (u32)idx[j];  // exact fp32 + np tie-break
      best = umin64(best, key);
    }
    out[wave] = (int)(u32)best;
  }
}

// ---------------------------------------------------------------- launch
extern "C" void kernel_launch(void* const* d_in, const int* in_sizes, int n_in,
                              void* d_out, int out_size, void* d_ws, size_t ws_size,
                              hipStream_t stream) {
  const float* x  = (const float*)d_in[0];
  const float* cb = (const float*)d_in[1];
  int* out = (int*)d_out;

  char* ws = (char*)d_ws;
  unsigned char* ch8  = (unsigned char*)(ws);
  unsigned char* xh8  = (unsigned char*)(ws + (size_t)4 * 1024 * 1024);
  float*         cnh  = (float*)(ws + (size_t)20 * 1024 * 1024);
  int*           cand = (int*)(ws + (size_t)20 * 1024 * 1024 + 32 * 1024);
  uint4*         part = (uint4*)(ws + (size_t)22 * 1024 * 1024);

  conv_codebook_kernel<<<KCODES / 4, 256, 0, stream>>>(cb, ch8, cnh);
  conv_x_kernel<<<(M_ROWS * DDIM) / (256 * 8), 256, 0, stream>>>(x, xh8);
  coarse_kernel<<<(M_ROWS / 256) * (KCODES / 256), 512, 0, stream>>>(xh8, ch8, cnh, part);
  merge_kernel<<<M_ROWS / 256, 256, 0, stream>>>(part, cand);
  rescore_kernel<<<M_ROWS / 4, 256, 0, stream>>>(x, cb, cnh, cand, out);
}

// Round 3
// 453.942 us; speedup vs baseline: 1.0471x; 1.0471x over previous
//
#include <hip/hip_runtime.h>
#include <hip/hip_bf16.h>
#include <hip/hip_fp16.h>

// Codebook argmin: x (32768,512) fp32, codebook (8192,512) fp32 -> codes (32768) int32
//
// v10: v9 (256x256-tile coarse, counted-vmcnt depth-2 pipeline) with the
// spill fixed: __launch_bounds__(512) lets the allocator use up to 256
// VGPR (v9's (512,2) clamped to 128 -> acc spilled to scratch: WRITE_SIZE
// 317 MB, MfmaUtil 16%). COMPUTE split into two tm-halves (af[4] live)
// keeps peak ~200 VGPR. XCD-aware block swizzle keeps each XCD's 4 B-panels
// (512 KB) L2-hot.
//
// ws layout:
//   ch8  : fp8 [8192][512]   @ 0        (4 MB)
//   xh8  : fp8 [32768][512]  @ 4 MB     (16 MB)
//   cnh  : f32 [8192]        @ 20 MB    (32 KB)
//   cand : int [32768][8]    @ 20M+32K  (1 MB)
//   part : uint4 [32][32768] @ 22 MB    (16 MB)

#define M_ROWS 32768
#define DDIM   512
#define KCODES 8192
#define NCAND  8

typedef unsigned long long u64;
typedef unsigned int u32;
typedef __attribute__((ext_vector_type(4))) float f32x4;
typedef __attribute__((ext_vector_type(8))) int v8i;

#define GL2LDS(gp, lp) __builtin_amdgcn_global_load_lds(                  \
    (const __attribute__((address_space(1))) void*)(gp),                  \
    (__attribute__((address_space(3))) void*)(lp), 16, 0, 0)

__device__ __forceinline__ u32 umin32(u32 a, u32 b) { return a < b ? a : b; }
__device__ __forceinline__ u32 umax32(u32 a, u32 b) { return a > b ? a : b; }
__device__ __forceinline__ u64 umin64(u64 a, u64 b) { return a < b ? a : b; }
__device__ __forceinline__ u32 umin3(u32 a, u32 b, u32 c) {  // fuses to v_min3_u32
  return umin32(umin32(a, b), c);
}
__device__ __forceinline__ u32 med3u(u32 a, u32 b, u32 c) {
  u32 d;
  asm("v_med3_u32 %0, %1, %2, %3" : "=v"(d) : "v"(a), "v"(b), "v"(c));
  return d;
}

// float -> order-preserving u32 (ascending); used only in rescore
__device__ __forceinline__ u32 fsort(float s) {
  u32 fb = __float_as_uint(s);
  return fb ^ (u32)(((int)fb >> 31) | 0x80000000);
}

// 8 floats -> 8 packed e4m3 bytes (uint2)
__device__ __forceinline__ uint2 pk8_fp8(float4 v0, float4 v1) {
  int lo = 0, hi = 0;
  lo = __builtin_amdgcn_cvt_pk_fp8_f32(v0.x, v0.y, lo, false);
  lo = __builtin_amdgcn_cvt_pk_fp8_f32(v0.z, v0.w, lo, true);
  hi = __builtin_amdgcn_cvt_pk_fp8_f32(v1.x, v1.y, hi, false);
  hi = __builtin_amdgcn_cvt_pk_fp8_f32(v1.z, v1.w, hi, true);
  return (uint2){(u32)lo, (u32)hi};
}

// ---------------------------------------------------------------- conv codebook
__global__ __launch_bounds__(256) void conv_codebook_kernel(
    const float* __restrict__ cb, unsigned char* __restrict__ ch8,
    float* __restrict__ cnh) {
  int wave = (blockIdx.x * 256 + threadIdx.x) >> 6;
  int lane = threadIdx.x & 63;
  if (wave >= KCODES) return;
  const float* src = cb + (size_t)wave * DDIM + lane * 8;
  float4 v0 = *(const float4*)(src);
  float4 v1 = *(const float4*)(src + 4);
  *(uint2*)(ch8 + (size_t)wave * DDIM + lane * 8) = pk8_fp8(v0, v1);
  float ss = v0.x*v0.x + v0.y*v0.y + v0.z*v0.z + v0.w*v0.w
           + v1.x*v1.x + v1.y*v1.y + v1.z*v1.z + v1.w*v1.w;
#pragma unroll
  for (int off = 32; off; off >>= 1) ss += __shfl_xor(ss, off);
  if (lane == 0) cnh[wave] = 0.5f * ss;
}

// ---------------------------------------------------------------- conv x
__global__ __launch_bounds__(256) void conv_x_kernel(
    const float* __restrict__ x, unsigned char* __restrict__ xh8) {
  size_t i = ((size_t)blockIdx.x * 256 + threadIdx.x) * 8;
  float4 v0 = *(const float4*)(x + i);
  float4 v1 = *(const float4*)(x + i + 4);
  *(uint2*)(xh8 + i) = pk8_fp8(v0, v1);
}

// LDS fragment load for K=128 MFMA: lane needs global k-bytes g*32..g*32+31
// of row `row` = granules q=g*2, g*2+1. LDS[row][slot]=global[row][slot^(row&7)]
// -> read slots (g*2)^(row&7) and that ^1. Combine two b128s into v8i.
__device__ __forceinline__ v8i ld_frag(const char* L, int row, int g) {
  const int base = row * 128;
  const int sl = ((g * 2) ^ (row & 7)) * 16;
  int4 lo = *(const int4*)&L[base + sl];
  int4 hi = *(const int4*)&L[base + (sl ^ 16)];
  v8i r;
  r[0] = lo.x; r[1] = lo.y; r[2] = lo.z; r[3] = lo.w;
  r[4] = hi.x; r[5] = hi.y; r[6] = hi.z; r[7] = hi.w;
  return r;
}

// ---------------------------------------------------------------- coarse GEMM
// Block: 512 threads = 8 waves as 2x4 (wm,wn); wave = 128x64 outputs as 8x4
// grid of 16x16x128 scaled-fp8 MFMA (scales = 1.0 -> exact e4m3 math).
// K=512 in 4 chunks of BK=128 bytes, double-buffered, depth-2 prefetch,
// counted vmcnt(8) (= one chunk's 8 GL2LDS per wave stays in flight).
__global__ __launch_bounds__(512) void coarse_kernel(
    const unsigned char* __restrict__ xh8, const unsigned char* __restrict__ ch8,
    const float* __restrict__ cnh, uint4* __restrict__ part) {
  // 131072 B: 2 x {aL(32K)+bL(32K)}; epilogue tab[256][17] uint4 (69632 B)
  // overlays (written only after all K-loop reads complete).
  __shared__ __align__(16) char smem[131072];
  uint4* tab = (uint4*)smem;

  const int tid  = threadIdx.x;
  const int lane = tid & 63;
  const int wid  = tid >> 6;
  const int wm   = wid >> 2, wn = wid & 3;
  const int g    = lane >> 4, l16 = lane & 15;

  // XCD-aware swizzle (4096 blocks, 4096%8==0 -> bijective): each XCD gets
  // a contiguous run of 512 orig-ids = 4 nblk panels (B working set 512 KB,
  // L2-resident per XCD).
  const int orig = (blockIdx.x & 7) * 512 + (blockIdx.x >> 3);
  const int mblk = orig & 127;
  const int nblk = orig >> 7;
  const int row0 = mblk * 256;
  const int col0 = nblk * 256;

  const int a_ = lane >> 3, b_ = lane & 7;
  // per-lane GL2LDS source: row +a_, granule b_^a_ of the current chunk
  const size_t gsrc = (size_t)a_ * DDIM + ((b_ ^ a_) << 4);
  const unsigned char* abase = xh8 + (size_t)row0 * DDIM + gsrc;
  const unsigned char* bbase = ch8 + (size_t)col0 * DDIM + gsrc;

// stage chunk cc (256 rows x 128 k-bytes of A and B) into buffer `buf`:
// 8 GL2LDS per wave (4 A + 4 B), wave wid covers rows [wid*32, wid*32+32)
#define STAGE(cc, buf) do {                                               \
    char* base_ = smem + (buf) * 65536;                                   \
    _Pragma("unroll")                                                     \
    for (int j = 0; j < 4; ++j) {                                         \
      const int R_ = wid * 32 + j * 8;                                    \
      const size_t off_ = (size_t)R_ * DDIM + (size_t)(cc) * 128;         \
      GL2LDS(abase + off_, base_ + R_ * 128);                             \
      GL2LDS(bbase + off_, base_ + 32768 + R_ * 128);                     \
    }                                                                     \
  } while (0)

#define WAITV(n) asm volatile("s_waitcnt vmcnt(" #n ")" ::: "memory")
#define RBAR() do {                                                       \
    __builtin_amdgcn_sched_barrier(0);                                    \
    __builtin_amdgcn_s_barrier();                                         \
    __builtin_amdgcn_sched_barrier(0);                                    \
  } while (0)

// Two tm-halves with af[4] live (peak VGPR ~200: acc 128 + af 32 + bf 8
// + addressing). bf re-read per half (+4 b128/wave/chunk, LDS has headroom).
#define COMPUTE(c) do {                                                   \
    const char* aL_ = smem + ((c) & 1) * 65536;                           \
    const char* bL_ = aL_ + 32768;                                        \
    _Pragma("unroll")                                                     \
    for (int h = 0; h < 2; ++h) {                                         \
      v8i af[4];                                                          \
      _Pragma("unroll")                                                   \
      for (int t = 0; t < 4; ++t)                                         \
        af[t] = ld_frag(aL_, wm * 128 + (h * 4 + t) * 16 + l16, g);       \
      _Pragma("unroll")                                                   \
      for (int tn = 0; tn < 4; ++tn) {                                    \
        v8i bf = ld_frag(bL_, wn * 64 + tn * 16 + l16, g);                \
        _Pragma("unroll")                                                 \
        for (int tm = 0; tm < 4; ++tm)                                    \
          acc[h * 4 + tm][tn] =                                           \
              __builtin_amdgcn_mfma_scale_f32_16x16x128_f8f6f4(           \
                  af[tm], bf, acc[h * 4 + tm][tn],                        \
                  0, 0,                     /* cbsz, blgp = fp8(e4m3) */  \
                  0, 0x7F7F7F7F,            /* opsel_a, scale_a = 1.0 */  \
                  0, 0x7F7F7F7F);           /* opsel_b, scale_b = 1.0 */  \
      }                                                                   \
    }                                                                     \
  } while (0)

  // codes + half-norms for this wave's 64 columns. These 4 vmem loads mix
  // into the vmcnt stream but only ADD to each counted drain (safe for
  // every issue-order interleave; verified case-by-case).
  u32 codev[4];
  float cn[4];
#pragma unroll
  for (int tn = 0; tn < 4; ++tn) {
    codev[tn] = (u32)(col0 + wn * 64 + tn * 16 + l16);
    cn[tn] = cnh[codev[tn]];
  }

  f32x4 acc[8][4];
#pragma unroll
  for (int tm = 0; tm < 8; ++tm)
#pragma unroll
    for (int tn = 0; tn < 4; ++tn) acc[tm][tn] = (f32x4){0.f, 0.f, 0.f, 0.f};

  STAGE(0, 0);
  STAGE(1, 1);

  WAITV(8);  RBAR();        // chunk0 landed (chunk1 stays in flight)
  COMPUTE(0);
  RBAR();                   // all waves done reading buf0
  STAGE(2, 0);

  WAITV(8);  RBAR();        // chunk1 landed (chunk2 in flight)
  COMPUTE(1);
  RBAR();                   // all waves done reading buf1
  STAGE(3, 1);

  WAITV(8);  RBAR();        // chunk2 landed (chunk3 in flight)
  COMPUTE(2);
  // no overwrite of buf0 follows -> no barrier needed here

  WAITV(0);  RBAR();        // chunk3 landed
  COMPUTE(3);

  // ---- epilogue phase 1: per-lane top-3 u32 keys over 4 cols x 32 rows ----
  // key = float_bits(s) & ~0x1FFF | code. s > 0 by 8-sigma margin.
  // Pair-insertion via min3/med3: top-3 of {a1<=a2<=a3, lo<=hi} is
  //   a1' = min(a1,lo); m = max(a1,lo);
  //   a2' = min3(a2,m,hi); a3' = min(a3, med3(a2,m,hi)).
  u32 k1[32], k2[32], k3[32];
#pragma unroll
  for (int tm = 0; tm < 8; ++tm)
#pragma unroll
    for (int r = 0; r < 4; ++r) {
      const int sl = tm * 4 + r;
      u32 key[4];
#pragma unroll
      for (int tn = 0; tn < 4; ++tn) {
        float s = cn[tn] - acc[tm][tn][r];
        key[tn] = (__float_as_uint(s) & 0xFFFFE000u) | codev[tn];
      }
      u32 a1 = umin32(key[0], key[1]);
      u32 a2 = umax32(key[0], key[1]);
      u32 a3 = ~0u;
      {
        u32 lo = umin32(key[2], key[3]), hi = umax32(key[2], key[3]);
        u32 m  = umax32(a1, lo);
        a1 = umin32(a1, lo);
        u32 b3 = med3u(a2, m, hi);
        a2 = umin3(a2, m, hi);
        a3 = umin32(a3, b3);
      }
      k1[sl] = a1; k2[sl] = a2; k3[sl] = a3;
    }

  // ---- epilogue phase 2: LDS-table reduce, four wn passes ----
  // merge sorted {v.x<=v.y<=v.z} into running sorted {m1<=m2<=m3}:
  //   m1' = min(m1,x); a = max(m1,x);
  //   m2' = min3(m2,a,y); m3' = min3(m3, med3(m2,a,y), z).
  u32 m1 = ~0u, m2 = ~0u, m3 = ~0u;
#pragma unroll
  for (int p = 0; p < 4; ++p) {
    __syncthreads();
    if (wn == p) {
#pragma unroll
      for (int tm = 0; tm < 8; ++tm)
#pragma unroll
        for (int r = 0; r < 4; ++r) {
          const int row = wm * 128 + tm * 16 + g * 4 + r;
          const int sl = tm * 4 + r;
          tab[row * 17 + l16] = (uint4){k1[sl], k2[sl], k3[sl], 0u};
        }
    }
    __syncthreads();
    if (tid < 256) {
#pragma unroll
      for (int e = 0; e < 16; ++e) {
        uint4 v = tab[tid * 17 + e];
        u32 a = umax32(m1, v.x);
        m1 = umin32(m1, v.x);
        u32 b = med3u(m2, a, v.y);
        m2 = umin3(m2, a, v.y);
        m3 = umin3(m3, b, v.z);
      }
    }
  }

  if (tid < 256)
    part[(size_t)nblk * M_ROWS + row0 + tid] = (uint4){m1, m2, m3, 0u};
#undef COMPUTE
#undef STAGE
#undef WAITV
#undef RBAR
}

// ---------------------------------------------------------------- merge: global top-8
__global__ __launch_bounds__(256) void merge_kernel(
    const uint4* __restrict__ part, int* __restrict__ cand) {
  const int row = blockIdx.x * 256 + threadIdx.x;
  u32 k[NCAND];
#pragma unroll
  for (int i = 0; i < NCAND; ++i) k[i] = ~0u;
  for (int nb = 0; nb < KCODES / 256; ++nb) {
    uint4 e = part[(size_t)nb * M_ROWS + row];
    u32 t = e.x;
#pragma unroll
    for (int i = 0; i < NCAND; ++i) { u32 mx = umax32(k[i], t); k[i] = umin32(k[i], t); t = mx; }
    t = e.y;
#pragma unroll
    for (int i = 0; i < NCAND; ++i) { u32 mx = umax32(k[i], t); k[i] = umin32(k[i], t); t = mx; }
    t = e.z;
#pragma unroll
    for (int i = 0; i < NCAND; ++i) { u32 mx = umax32(k[i], t); k[i] = umin32(k[i], t); t = mx; }
  }
#pragma unroll
  for (int i = 0; i < NCAND; ++i)
    cand[row * NCAND + i] = (int)(k[i] & 0x1FFFu);
}

// ---------------------------------------------------------------- fp32 rescore (8)
__global__ __launch_bounds__(256) void rescore_kernel(
    const float* __restrict__ x, const float* __restrict__ cb,
    const float* __restrict__ cnh, const int* __restrict__ cand,
    int* __restrict__ out) {
  int wave = (blockIdx.x * 256 + threadIdx.x) >> 6;
  int lane = threadIdx.x & 63;
  if (wave >= M_ROWS) return;
  int idx[NCAND];
#pragma unroll
  for (int j = 0; j < NCAND; ++j) idx[j] = cand[wave * NCAND + j];

  const float* xr = x + (size_t)wave * DDIM + lane * 8;
  float4 x0 = *(const float4*)(xr);
  float4 x1 = *(const float4*)(xr + 4);

  float d[NCAND];
#pragma unroll
  for (int j = 0; j < NCAND; ++j) {
    const float* c = cb + (size_t)idx[j] * DDIM + lane * 8;
    float4 a0 = *(const float4*)(c);
    float4 a1 = *(const float4*)(c + 4);
    d[j] = x0.x*a0.x + x0.y*a0.y + x0.z*a0.z + x0.w*a0.w
         + x1.x*a1.x + x1.y*a1.y + x1.z*a1.z + x1.w*a1.w;
  }
#pragma unroll
  for (int off = 32; off; off >>= 1)
#pragma unroll
    for (int j = 0; j < NCAND; ++j) d[j] += __shfl_xor(d[j], off);

  if (lane == 0) {
    u64 best = ~0ull;
#pragma unroll
    for (int j = 0; j < NCAND; ++j) {
      float s = cnh[idx[j]] - d[j];
      u64 key = ((u64)fsort(s) << 32) | (u32)idx[j];  // exact fp32 + np tie-break
      best = umin64(best, key);
    }
    out[wave] = (int)(u32)best;
  }
}

// ---------------------------------------------------------------- launch
extern "C" void kernel_launch(void* const* d_in, const int* in_sizes, int n_in,
                              void* d_out, int out_size, void* d_ws, size_t ws_size,
                              hipStream_t stream) {
  const float* x  = (const float*)d_in[0];
  const float* cb = (const float*)d_in[1];
  int* out = (int*)d_out;

  char* ws = (char*)d_ws;
  unsigned char* ch8  = (unsigned char*)(ws);
  unsigned char* xh8  = (unsigned char*)(ws + (size_t)4 * 1024 * 1024);
  float*         cnh  = (float*)(ws + (size_t)20 * 1024 * 1024);
  int*           cand = (int*)(ws + (size_t)20 * 1024 * 1024 + 32 * 1024);
  uint4*         part = (uint4*)(ws + (size_t)22 * 1024 * 1024);

  conv_codebook_kernel<<<KCODES / 4, 256, 0, stream>>>(cb, ch8, cnh);
  conv_x_kernel<<<(M_ROWS * DDIM) / (256 * 8), 256, 0, stream>>>(x, xh8);
  coarse_kernel<<<(M_ROWS / 256) * (KCODES / 256), 512, 0, stream>>>(xh8, ch8, cnh, part);
  merge_kernel<<<M_ROWS / 256, 256, 0, stream>>>(part, cand);
  rescore_kernel<<<M_ROWS / 4, 256, 0, stream>>>(x, cb, cnh, cand, out);
}